// Round 1
// baseline (1428.106 us; speedup 1.0000x reference)
//
#include <hip/hip_runtime.h>

#define NFEAT 128
#define HID 16
#define NOUT 2
#define NGRAPH 64

// ---------------- init: deg=1 (self loop), zero pool accumulators ----------
__global__ __launch_bounds__(256) void k_init(float* deg, float* psums, float* pcnt, int N) {
    int i = blockIdx.x * 256 + threadIdx.x;
    if (i < N) deg[i] = 1.0f;
    if (i < NGRAPH * NOUT) psums[i] = 0.0f;
    if (i < NGRAPH) pcnt[i] = 0.0f;
}

// ---------------- degree: deg[dst] += 1 ------------------------------------
__global__ __launch_bounds__(256) void k_deg(const int* __restrict__ dst, float* __restrict__ deg, int E) {
    int e = blockIdx.x * 256 + threadIdx.x;
    if (e < E) atomicAdd(&deg[dst[e]], 1.0f);
}

// ---------------- dinv = 1/sqrt(deg) (in place) -----------------------------
__global__ __launch_bounds__(256) void k_dinv(float* deg, int N) {
    int i = blockIdx.x * 256 + threadIdx.x;
    if (i < N) deg[i] = 1.0f / sqrtf(deg[i]);
}

// ---------------- h1 = x @ W1; agg1 = h1 * dinv^2 (self-loop init) ---------
// block = 256 threads = 16 nodes x 16 hidden
__global__ __launch_bounds__(256) void k_xw1(const float* __restrict__ x, const float* __restrict__ W1,
                                             const float* __restrict__ dinv,
                                             float* __restrict__ h1, float* __restrict__ agg1, int N) {
    __shared__ float sW[NFEAT * HID];          // 8 KB
    __shared__ float sx[16 * 132];             // 16 rows, +4 pad to break bank aliasing
    int t = threadIdx.x;
    #pragma unroll
    for (int i = 0; i < NFEAT * HID; i += 256) sW[i + t] = W1[i + t];

    int local = t >> 4;        // node within block
    int h     = t & 15;        // hidden index / stage-column group
    int n = blockIdx.x * 16 + local;

    if (n < N) {
        const float4* xr = (const float4*)(x + (size_t)n * NFEAT);
        float4 a = xr[h * 2];
        float4 b = xr[h * 2 + 1];
        float* sp = sx + local * 132 + h * 8;
        ((float4*)sp)[0] = a;
        ((float4*)sp)[1] = b;
    }
    __syncthreads();
    if (n >= N) return;

    const float* row = sx + local * 132;
    float acc = 0.0f;
    #pragma unroll
    for (int k = 0; k < NFEAT; k++) acc += row[k] * sW[k * HID + h];

    float di = dinv[n];
    h1[(size_t)n * HID + h]   = acc;
    agg1[(size_t)n * HID + h] = acc * di * di;   // self-loop: norm = dinv^2
}

// ---------------- edge pass 1: agg1[dst] += h1[src]*norm, 16 feats ---------
// 16 threads per edge, one feature each
__global__ __launch_bounds__(256) void k_edge1(const int* __restrict__ src, const int* __restrict__ dst,
                                               const float* __restrict__ dinv, const float* __restrict__ h1,
                                               float* __restrict__ agg1, int E) {
    int gid = blockIdx.x * 256 + threadIdx.x;
    int e = gid >> 4;
    if (e >= E) return;
    int f = gid & 15;
    int s = src[e];
    int d = dst[e];
    float nm = dinv[s] * dinv[d];
    atomicAdd(&agg1[d * HID + f], h1[s * HID + f] * nm);
}

// ---------------- PReLU(agg1+b1) @ W2 ; agg2 self-loop init ----------------
__global__ __launch_bounds__(256) void k_mid(const float* __restrict__ agg1, const float* __restrict__ b1,
                                             const float* __restrict__ prelu_a, const float* __restrict__ W2,
                                             const float* __restrict__ dinv,
                                             float* __restrict__ t2, float* __restrict__ agg2, int N) {
    int n = blockIdx.x * 256 + threadIdx.x;
    if (n >= N) return;
    float a = prelu_a[0];
    float v[HID];
    const float4* p = (const float4*)(agg1 + (size_t)n * HID);
    #pragma unroll
    for (int i = 0; i < 4; i++) {
        float4 q = p[i];
        v[4 * i + 0] = q.x; v[4 * i + 1] = q.y; v[4 * i + 2] = q.z; v[4 * i + 3] = q.w;
    }
    float o0 = 0.0f, o1 = 0.0f;
    #pragma unroll
    for (int i = 0; i < HID; i++) {
        float tv = v[i] + b1[i];
        tv = (tv >= 0.0f) ? tv : a * tv;
        o0 += tv * W2[i * 2 + 0];
        o1 += tv * W2[i * 2 + 1];
    }
    float di = dinv[n];
    float sl = di * di;
    t2[n * 2 + 0] = o0;
    t2[n * 2 + 1] = o1;
    agg2[n * 2 + 0] = o0 * sl;
    agg2[n * 2 + 1] = o1 * sl;
}

// ---------------- edge pass 2: agg2[dst] += t2[src]*norm, 2 feats ----------
__global__ __launch_bounds__(256) void k_edge2(const int* __restrict__ src, const int* __restrict__ dst,
                                               const float* __restrict__ dinv, const float* __restrict__ t2,
                                               float* __restrict__ agg2, int E) {
    int e = blockIdx.x * 256 + threadIdx.x;
    if (e >= E) return;
    int s = src[e];
    int d = dst[e];
    float nm = dinv[s] * dinv[d];
    float2 vv = *(const float2*)(t2 + (size_t)s * 2);
    atomicAdd(&agg2[d * 2 + 0], vv.x * nm);
    atomicAdd(&agg2[d * 2 + 1], vv.y * nm);
}

// ---------------- pool: LDS-binned per-graph sums + counts -----------------
__global__ __launch_bounds__(256) void k_pool(const float* __restrict__ agg2, const int* __restrict__ batch,
                                              float* __restrict__ psums, float* __restrict__ pcnt, int N) {
    __shared__ float ls[NGRAPH * NOUT];
    __shared__ float lc[NGRAPH];
    int t = threadIdx.x;
    if (t < NGRAPH * NOUT) ls[t] = 0.0f;
    if (t < NGRAPH) lc[t] = 0.0f;
    __syncthreads();
    int n = blockIdx.x * 256 + t;
    if (n < N) {
        int g = batch[n];
        float2 vv = *(const float2*)(agg2 + (size_t)n * 2);
        atomicAdd(&ls[g * 2 + 0], vv.x);
        atomicAdd(&ls[g * 2 + 1], vv.y);
        atomicAdd(&lc[g], 1.0f);
    }
    __syncthreads();
    if (t < NGRAPH * NOUT && ls[t] != 0.0f) atomicAdd(&psums[t], ls[t]);
    if (t < NGRAPH && lc[t] != 0.0f) atomicAdd(&pcnt[t], lc[t]);
}

// ---------------- final: out = (sum + cnt*b2)/max(cnt,1) -------------------
__global__ __launch_bounds__(128) void k_final(const float* __restrict__ psums, const float* __restrict__ pcnt,
                                               const float* __restrict__ b2, float* __restrict__ out) {
    int t = threadIdx.x;
    if (t < NGRAPH * NOUT) {
        int g = t >> 1, c = t & 1;
        float cnt = pcnt[g];
        out[t] = (psums[t] + cnt * b2[c]) / fmaxf(cnt, 1.0f);
    }
}

extern "C" void kernel_launch(void* const* d_in, const int* in_sizes, int n_in,
                              void* d_out, int out_size, void* d_ws, size_t ws_size,
                              hipStream_t stream) {
    const float* x       = (const float*)d_in[0];
    const float* W1      = (const float*)d_in[1];
    const float* b1      = (const float*)d_in[2];
    const float* prelu_a = (const float*)d_in[3];
    const float* W2      = (const float*)d_in[4];
    const float* b2      = (const float*)d_in[5];
    const int*   ei      = (const int*)d_in[6];
    const int*   batch   = (const int*)d_in[7];

    const int N = in_sizes[7];          // 100000
    const int E = in_sizes[6] / 2;      // 6400000
    const int* src = ei;
    const int* dst = ei + E;

    // workspace layout (floats)
    float* ws    = (float*)d_ws;
    float* deg   = ws;                        // N   (becomes dinv in place)
    float* h1    = deg + N;                   // N*16
    float* agg1  = h1 + (size_t)N * HID;      // N*16
    float* t2    = agg1 + (size_t)N * HID;    // N*2
    float* agg2  = t2 + (size_t)N * NOUT;     // N*2
    float* psums = agg2 + (size_t)N * NOUT;   // 128
    float* pcnt  = psums + NGRAPH * NOUT;     // 64

    float* out = (float*)d_out;

    int nb_nodes = (N + 255) / 256;
    int nb_edges = (E + 255) / 256;

    k_init<<<nb_nodes, 256, 0, stream>>>(deg, psums, pcnt, N);
    k_deg<<<nb_edges, 256, 0, stream>>>(dst, deg, E);
    k_dinv<<<nb_nodes, 256, 0, stream>>>(deg, N);
    k_xw1<<<(N + 15) / 16, 256, 0, stream>>>(x, W1, deg, h1, agg1, N);
    k_edge1<<<((size_t)E * 16 + 255) / 256, 256, 0, stream>>>(src, dst, deg, h1, agg1, E);
    k_mid<<<nb_nodes, 256, 0, stream>>>(agg1, b1, prelu_a, W2, deg, t2, agg2, N);
    k_edge2<<<nb_edges, 256, 0, stream>>>(src, dst, deg, t2, agg2, E);
    k_pool<<<nb_nodes, 256, 0, stream>>>(agg2, batch, psums, pcnt, N);
    k_final<<<1, 128, 0, stream>>>(psums, pcnt, b2, out);
}

// Round 2
// 890.230 us; speedup vs baseline: 1.6042x; 1.6042x over previous
//
#include <hip/hip_runtime.h>

#define NFEAT 128
#define HID 16
#define NOUT 2
#define NGRAPH 64

// ---------------- init: deg=1 (self loop), zero pool accumulators ----------
__global__ __launch_bounds__(256) void k_init(float* deg, float* psums, float* pcnt, int N) {
    int i = blockIdx.x * 256 + threadIdx.x;
    if (i < N) deg[i] = 1.0f;
    if (i < NGRAPH * NOUT) psums[i] = 0.0f;
    if (i < NGRAPH) pcnt[i] = 0.0f;
}

// ---------------- degree: deg[dst] += 1 ------------------------------------
__global__ __launch_bounds__(256) void k_deg(const int* __restrict__ dst, float* __restrict__ deg, int E) {
    int e = blockIdx.x * 256 + threadIdx.x;
    if (e < E) atomicAdd(&deg[dst[e]], 1.0f);
}

// ---------------- dinv = 1/sqrt(deg) (in place) -----------------------------
__global__ __launch_bounds__(256) void k_dinv(float* deg, int N) {
    int i = blockIdx.x * 256 + threadIdx.x;
    if (i < N) deg[i] = 1.0f / sqrtf(deg[i]);
}

// ---------------- h1s = dinv * (x @ W1); agg1 init = h1s (self loop) -------
// block = 256 threads = 16 nodes x 16 hidden
__global__ __launch_bounds__(256) void k_xw1(const float* __restrict__ x, const float* __restrict__ W1,
                                             const float* __restrict__ dinv,
                                             float* __restrict__ h1s, float* __restrict__ agg1, int N) {
    __shared__ float sW[NFEAT * HID];          // 8 KB
    __shared__ float sx[16 * 132];             // 16 rows, +4 pad
    int t = threadIdx.x;
    #pragma unroll
    for (int i = 0; i < NFEAT * HID; i += 256) sW[i + t] = W1[i + t];

    int local = t >> 4;        // node within block
    int h     = t & 15;        // hidden index
    int n = blockIdx.x * 16 + local;

    if (n < N) {
        const float4* xr = (const float4*)(x + (size_t)n * NFEAT);
        float4 a = xr[h * 2];
        float4 b = xr[h * 2 + 1];
        float* sp = sx + local * 132 + h * 8;
        ((float4*)sp)[0] = a;
        ((float4*)sp)[1] = b;
    }
    __syncthreads();
    if (n >= N) return;

    const float* row = sx + local * 132;
    float acc = 0.0f;
    #pragma unroll
    for (int k = 0; k < NFEAT; k++) acc += row[k] * sW[k * HID + h];

    float v = acc * dinv[n];                  // h1s = dinv[n] * h1[n]
    h1s[(size_t)n * HID + h]  = v;
    agg1[(size_t)n * HID + h] = v;            // self-loop term (dinv[d] applied in k_mid)
}

// ---------------- edge pass 1: agg1[dst] += h1s[src] (no dinv gathers) -----
// 16 threads per edge, one feature each; one 64B-line atomic per edge
__global__ __launch_bounds__(256) void k_edge1(const int* __restrict__ src, const int* __restrict__ dst,
                                               const float* __restrict__ h1s,
                                               float* __restrict__ agg1, int E) {
    int gid = blockIdx.x * 256 + threadIdx.x;
    int e = gid >> 4;
    if (e >= E) return;
    int f = gid & 15;
    int s = src[e];
    int d = dst[e];
    atomicAdd(&agg1[d * HID + f], h1s[s * HID + f]);
}

// ---------------- PReLU(dinv[d]*agg1 + b1) @ W2 ; t2s = dinv*t2 ------------
// also folds pooling self-loop term dinv[n]*t2s[n] and node counts (LDS-binned)
__global__ __launch_bounds__(256) void k_mid(const float* __restrict__ agg1, const float* __restrict__ b1,
                                             const float* __restrict__ prelu_a, const float* __restrict__ W2,
                                             const float* __restrict__ dinv, const int* __restrict__ batch,
                                             float* __restrict__ t2s,
                                             float* __restrict__ psums, float* __restrict__ pcnt, int N) {
    __shared__ float ls[NGRAPH * NOUT];
    __shared__ float lc[NGRAPH];
    int t = threadIdx.x;
    if (t < NGRAPH * NOUT) ls[t] = 0.0f;
    if (t < NGRAPH) lc[t] = 0.0f;
    __syncthreads();

    int n = blockIdx.x * 256 + t;
    if (n < N) {
        float a = prelu_a[0];
        float di = dinv[n];
        float v[HID];
        const float4* p = (const float4*)(agg1 + (size_t)n * HID);
        #pragma unroll
        for (int i = 0; i < 4; i++) {
            float4 q = p[i];
            v[4 * i + 0] = q.x; v[4 * i + 1] = q.y; v[4 * i + 2] = q.z; v[4 * i + 3] = q.w;
        }
        float o0 = 0.0f, o1 = 0.0f;
        #pragma unroll
        for (int i = 0; i < HID; i++) {
            float tv = di * v[i] + b1[i];       // apply dinv[d] factored out of edge pass
            tv = (tv >= 0.0f) ? tv : a * tv;
            o0 += tv * W2[i * 2 + 0];
            o1 += tv * W2[i * 2 + 1];
        }
        float s0 = di * o0, s1 = di * o1;       // t2s = dinv * t2
        t2s[n * 2 + 0] = s0;
        t2s[n * 2 + 1] = s1;
        int g = batch[n];
        atomicAdd(&ls[g * 2 + 0], di * s0);     // self-loop: dinv^2 * t2
        atomicAdd(&ls[g * 2 + 1], di * s1);
        atomicAdd(&lc[g], 1.0f);
    }
    __syncthreads();
    if (t < NGRAPH * NOUT) atomicAdd(&psums[t], ls[t]);
    if (t < NGRAPH) atomicAdd(&pcnt[t], lc[t]);
}

// ---------------- edge pass 2 fused with pool: LDS-binned per-graph sums ---
// psums[batch[d]] += dinv[d] * t2s[s]  — no global scatter to agg2 at all
#define E2_BLOCKS 2048
__global__ __launch_bounds__(256) void k_e2pool(const int* __restrict__ src, const int* __restrict__ dst,
                                                const float* __restrict__ dinv, const float* __restrict__ t2s,
                                                const int* __restrict__ batch,
                                                float* __restrict__ psums, int E) {
    __shared__ float ls[NGRAPH * NOUT];
    int t = threadIdx.x;
    if (t < NGRAPH * NOUT) ls[t] = 0.0f;
    __syncthreads();

    int stride = E2_BLOCKS * 256;
    for (int e = blockIdx.x * 256 + t; e < E; e += stride) {
        int s = src[e];
        int d = dst[e];
        float dd = dinv[d];
        float2 vv = *(const float2*)(t2s + (size_t)s * 2);
        int g = batch[d];
        atomicAdd(&ls[g * 2 + 0], dd * vv.x);
        atomicAdd(&ls[g * 2 + 1], dd * vv.y);
    }
    __syncthreads();
    if (t < NGRAPH * NOUT) atomicAdd(&psums[t], ls[t]);
}

// ---------------- final: out = (sum + cnt*b2)/max(cnt,1) -------------------
__global__ __launch_bounds__(128) void k_final(const float* __restrict__ psums, const float* __restrict__ pcnt,
                                               const float* __restrict__ b2, float* __restrict__ out) {
    int t = threadIdx.x;
    if (t < NGRAPH * NOUT) {
        int g = t >> 1, c = t & 1;
        float cnt = pcnt[g];
        out[t] = (psums[t] + cnt * b2[c]) / fmaxf(cnt, 1.0f);
    }
}

extern "C" void kernel_launch(void* const* d_in, const int* in_sizes, int n_in,
                              void* d_out, int out_size, void* d_ws, size_t ws_size,
                              hipStream_t stream) {
    const float* x       = (const float*)d_in[0];
    const float* W1      = (const float*)d_in[1];
    const float* b1      = (const float*)d_in[2];
    const float* prelu_a = (const float*)d_in[3];
    const float* W2      = (const float*)d_in[4];
    const float* b2      = (const float*)d_in[5];
    const int*   ei      = (const int*)d_in[6];
    const int*   batch   = (const int*)d_in[7];

    const int N = in_sizes[7];          // 100000
    const int E = in_sizes[6] / 2;      // 6400000
    const int* src = ei;
    const int* dst = ei + E;

    // workspace layout (floats)
    float* ws    = (float*)d_ws;
    float* deg   = ws;                        // N   (becomes dinv in place)
    float* h1s   = deg + N;                   // N*16
    float* agg1  = h1s + (size_t)N * HID;     // N*16
    float* t2s   = agg1 + (size_t)N * HID;    // N*2
    float* psums = t2s + (size_t)N * NOUT;    // 128
    float* pcnt  = psums + NGRAPH * NOUT;     // 64

    float* out = (float*)d_out;

    int nb_nodes = (N + 255) / 256;
    int nb_edges = (E + 255) / 256;

    k_init<<<nb_nodes, 256, 0, stream>>>(deg, psums, pcnt, N);
    k_deg<<<nb_edges, 256, 0, stream>>>(dst, deg, E);
    k_dinv<<<nb_nodes, 256, 0, stream>>>(deg, N);
    k_xw1<<<(N + 15) / 16, 256, 0, stream>>>(x, W1, deg, h1s, agg1, N);
    k_edge1<<<((size_t)E * 16 + 255) / 256, 256, 0, stream>>>(src, dst, h1s, agg1, E);
    k_mid<<<nb_nodes, 256, 0, stream>>>(agg1, b1, prelu_a, W2, deg, batch, t2s, psums, pcnt, N);
    k_e2pool<<<E2_BLOCKS, 256, 0, stream>>>(src, dst, deg, t2s, batch, psums, E);
    k_final<<<1, 128, 0, stream>>>(psums, pcnt, b2, out);
}